// Round 1
// baseline (7757.088 us; speedup 1.0000x reference)
//
#include <hip/hip_runtime.h>
#include <math.h>

constexpr int B_ = 32, T_ = 512, N_ = 7, BN_ = 224;
constexpr int L_ = 64, DM_ = 32, PLEN_ = 16;
constexpr int HF_ = 256, NH_ = 8, DFF_ = 32;
constexpr int S_ = 1000, DLLM_ = 4096, V_ = 32000;
constexpr int PRED_ = 96, HNF_ = 2048;
constexpr int KSPLIT = 16, KCH = 2000;   // GEMM2 split-K: 16 chunks * 2000 = 32000

// ---------------- stats: mean/stdev per (b,n) ----------------
__global__ __launch_bounds__(256) void k_stats(const float* __restrict__ x,
                                               float* __restrict__ mean_o,
                                               float* __restrict__ std_o) {
    int bn = blockIdx.x, b = bn / N_, n = bn % N_;
    const float* xp = x + (size_t)b * T_ * N_ + n;
    float s = 0.f, sq = 0.f;
    for (int t = threadIdx.x; t < T_; t += 256) { float v = xp[(size_t)t * N_]; s += v; sq += v * v; }
    for (int o = 32; o > 0; o >>= 1) { s += __shfl_down(s, o, 64); sq += __shfl_down(sq, o, 64); }
    __shared__ float rs[4], rq[4];
    int wid = threadIdx.x >> 6, lane = threadIdx.x & 63;
    if (lane == 0) { rs[wid] = s; rq[wid] = sq; }
    __syncthreads();
    if (threadIdx.x == 0) {
        float S = rs[0] + rs[1] + rs[2] + rs[3];
        float Q = rq[0] + rq[1] + rq[2] + rq[3];
        float m = S / T_;
        float var = Q / T_ - m * m;
        mean_o[bn] = m;
        std_o[bn] = sqrtf(var + 1e-5f);
    }
}

// ---------------- wsum[c] = sum_d wkv[c][d] (for map_b folding) ----------------
__global__ __launch_bounds__(256) void k_wsum(const float* __restrict__ wk,
                                              const float* __restrict__ wv,
                                              float* __restrict__ wsum) {
    int c = blockIdx.x;
    const float* row = (c < HF_) ? wk + (size_t)c * DLLM_ : wv + (size_t)(c - HF_) * DLLM_;
    float s = 0.f;
    for (int d = threadIdx.x; d < DLLM_; d += 256) s += row[d];
    for (int o = 32; o > 0; o >>= 1) s += __shfl_down(s, o, 64);
    __shared__ float rs[4];
    int wid = threadIdx.x >> 6, lane = threadIdx.x & 63;
    if (lane == 0) rs[wid] = s;
    __syncthreads();
    if (threadIdx.x == 0) wsum[c] = rs[0] + rs[1] + rs[2] + rs[3];
}

// ---------------- normalize + patch + conv embed: enc[bn][l][o] ----------------
__global__ __launch_bounds__(256) void k_enc(const float* __restrict__ x,
                                             const float* __restrict__ conv_w,
                                             const float* __restrict__ mean_i,
                                             const float* __restrict__ std_i,
                                             float* __restrict__ enc) {
    int bn = blockIdx.x, b = bn / N_, n = bn % N_;
    __shared__ float xn[520];
    __shared__ float cw[DM_ * PLEN_ * 3];  // [o][i][t] = o*48+i*3+t
    float m = mean_i[bn], rstd = 1.0f / std_i[bn];
    for (int i = threadIdx.x; i < DM_ * PLEN_ * 3; i += 256) cw[i] = conv_w[i];
    const float* xp = x + (size_t)b * T_ * N_ + n;
    for (int t = threadIdx.x; t < T_; t += 256) xn[t] = (xp[(size_t)t * N_] - m) * rstd;
    __syncthreads();
    if (threadIdx.x < 8) xn[T_ + threadIdx.x] = xn[T_ - 1];
    __syncthreads();
    for (int idx = threadIdx.x; idx < L_ * DM_; idx += 256) {
        int l = idx >> 5, o = idx & 31;
        float acc = 0.f;
        #pragma unroll
        for (int t = 0; t < 3; t++) {
            int col = l + t;  // padded col 0..65
            int pcol = (col == 0) ? 63 : ((col == 65) ? 0 : col - 1);
            const float* xb = &xn[pcol * 8];
            const float* cwb = &cw[o * 48 + t];
            #pragma unroll
            for (int i = 0; i < 16; i++) acc += xb[i] * cwb[i * 3];
        }
        enc[(size_t)bn * 2048 + idx] = acc;
    }
}

// ---------------- q = (enc @ wq^T + bq) * scale ----------------
__global__ __launch_bounds__(256) void k_q(const float* __restrict__ enc,
                                           const float* __restrict__ wq,
                                           const float* __restrict__ bq,
                                           float* __restrict__ qo) {
    int bn = blockIdx.x;
    __shared__ float et[2048];
    __shared__ float wqs[HF_ * DM_];
    for (int i = threadIdx.x; i < 2048; i += 256) et[i] = enc[(size_t)bn * 2048 + i];
    for (int i = threadIdx.x; i < HF_ * DM_; i += 256) wqs[i] = wq[i];
    __syncthreads();
    const float scale = 0.17677669529663687f;  // 1/sqrt(32)
    for (int idx = threadIdx.x; idx < L_ * HF_; idx += 256) {
        int l = idx >> 8, c = idx & 255;
        float acc = bq[c];
        const float* e = &et[l * 32];
        const float* w = &wqs[c * 32];
        #pragma unroll
        for (int k = 0; k < 32; k++) acc += e[k] * w[k];
        qo[(size_t)bn * L_ * HF_ + idx] = acc * scale;
    }
}

// ---------------- GEMM1: E[32000][512] = word_emb @ [wk;wv]^T ----------------
// 128x128 tile, KT=16, 8x8 micro, both operands K-major transposed in LDS.
__global__ __launch_bounds__(256) void k_gemm1(const float* __restrict__ A,
                                               const float* __restrict__ Wk,
                                               const float* __restrict__ Wv,
                                               float* __restrict__ C) {
    __shared__ float As[16][136];
    __shared__ float Bs[16][136];
    const int m0 = blockIdx.x * 128, n0 = blockIdx.y * 128;
    const float* Brow = (n0 < HF_) ? Wk + (size_t)n0 * DLLM_ : Wv + (size_t)(n0 - HF_) * DLLM_;
    const int tid = threadIdx.x, tx = tid & 15, ty = tid >> 4;
    float acc[8][8] = {};
    for (int k0 = 0; k0 < DLLM_; k0 += 16) {
        #pragma unroll
        for (int i = 0; i < 2; i++) {
            int f = i * 256 + tid;
            int r = f >> 2, c = (f & 3) * 4;
            float4 av = *(const float4*)(A + (size_t)(m0 + r) * DLLM_ + k0 + c);
            float4 bv = *(const float4*)(Brow + (size_t)r * DLLM_ + k0 + c);
            As[c + 0][r] = av.x; As[c + 1][r] = av.y; As[c + 2][r] = av.z; As[c + 3][r] = av.w;
            Bs[c + 0][r] = bv.x; Bs[c + 1][r] = bv.y; Bs[c + 2][r] = bv.z; Bs[c + 3][r] = bv.w;
        }
        __syncthreads();
        #pragma unroll
        for (int kk = 0; kk < 16; kk++) {
            float4 a0 = *(const float4*)&As[kk][ty * 8];
            float4 a1 = *(const float4*)&As[kk][ty * 8 + 4];
            float4 b0 = *(const float4*)&Bs[kk][tx * 8];
            float4 b1 = *(const float4*)&Bs[kk][tx * 8 + 4];
            float a[8] = {a0.x, a0.y, a0.z, a0.w, a1.x, a1.y, a1.z, a1.w};
            float b[8] = {b0.x, b0.y, b0.z, b0.w, b1.x, b1.y, b1.z, b1.w};
            #pragma unroll
            for (int i2 = 0; i2 < 8; i2++)
                #pragma unroll
                for (int j = 0; j < 8; j++) acc[i2][j] += a[i2] * b[j];
        }
        __syncthreads();
    }
    for (int i2 = 0; i2 < 8; i2++) {
        size_t m = m0 + ty * 8 + i2;
        float* crow = C + m * 512 + n0 + tx * 8;
        #pragma unroll
        for (int j = 0; j < 8; j++) crow[j] = acc[i2][j];
    }
}

// ---------------- GEMM2 (split-K partials): Cp[z] += map_w[:,chunk] @ E[chunk,:] ----------------
__global__ __launch_bounds__(256) void k_gemm2(const float* __restrict__ A,
                                               const float* __restrict__ B,
                                               float* __restrict__ Cp) {
    __shared__ float As[16][136];
    __shared__ float Bs[16][136];
    const int m0 = blockIdx.x * 128, n0 = blockIdx.y * 128;
    const int kz = blockIdx.z;
    const int kbeg = kz * KCH, kend = kbeg + KCH;
    const int tid = threadIdx.x, tx = tid & 15, ty = tid >> 4;
    float acc[8][8] = {};
    for (int k0 = kbeg; k0 < kend; k0 += 16) {
        #pragma unroll
        for (int i = 0; i < 2; i++) {
            int f = i * 256 + tid;
            int r = f >> 2, c = (f & 3) * 4;
            int m = m0 + r;
            float4 av = (m < S_) ? *(const float4*)(A + (size_t)m * V_ + k0 + c)
                                 : make_float4(0.f, 0.f, 0.f, 0.f);
            As[c + 0][r] = av.x; As[c + 1][r] = av.y; As[c + 2][r] = av.z; As[c + 3][r] = av.w;
            int rk = f >> 5, cn = (f & 31) * 4;  // B row-major [K][512]
            float4 bv = *(const float4*)(B + (size_t)(k0 + rk) * 512 + n0 + cn);
            *(float4*)&Bs[rk][cn] = bv;
        }
        __syncthreads();
        #pragma unroll
        for (int kk = 0; kk < 16; kk++) {
            float4 a0 = *(const float4*)&As[kk][ty * 8];
            float4 a1 = *(const float4*)&As[kk][ty * 8 + 4];
            float4 b0 = *(const float4*)&Bs[kk][tx * 8];
            float4 b1 = *(const float4*)&Bs[kk][tx * 8 + 4];
            float a[8] = {a0.x, a0.y, a0.z, a0.w, a1.x, a1.y, a1.z, a1.w};
            float b[8] = {b0.x, b0.y, b0.z, b0.w, b1.x, b1.y, b1.z, b1.w};
            #pragma unroll
            for (int i2 = 0; i2 < 8; i2++)
                #pragma unroll
                for (int j = 0; j < 8; j++) acc[i2][j] += a[i2] * b[j];
        }
        __syncthreads();
    }
    for (int i2 = 0; i2 < 8; i2++) {
        int m = m0 + ty * 8 + i2;
        if (m < S_) {
            float* crow = Cp + ((size_t)kz * S_ + m) * 512 + n0 + tx * 8;
            #pragma unroll
            for (int j = 0; j < 8; j++) crow[j] = acc[i2][j];
        }
    }
}

// ---------------- reduce split-K + bias: KV[t][c] ----------------
__global__ __launch_bounds__(256) void k_red(const float* __restrict__ Cp,
                                             const float* __restrict__ mb,
                                             const float* __restrict__ wsum,
                                             const float* __restrict__ bk,
                                             const float* __restrict__ bv,
                                             float* __restrict__ KV) {
    int idx = blockIdx.x * 256 + threadIdx.x;
    if (idx >= S_ * 512) return;
    int m = idx >> 9, n = idx & 511;
    float s = 0.f;
    #pragma unroll
    for (int z = 0; z < KSPLIT; z++) s += Cp[(size_t)z * S_ * 512 + idx];
    float bias = (n < HF_) ? bk[n] : bv[n - HF_];
    KV[idx] = s + mb[m] * wsum[n] + bias;
}

// ---------------- attention per (bn,l): scores -> softmax -> rep -> out32 ----------------
__global__ __launch_bounds__(256) void k_attn(const float* __restrict__ q,
                                              const float* __restrict__ kv,
                                              const float* __restrict__ wo,
                                              const float* __restrict__ bo,
                                              float* __restrict__ out32) {
    int l = blockIdx.x, bn = blockIdx.y;
    __shared__ float ql[256];
    __shared__ float sc[NH_][S_];
    __shared__ float rden[NH_];
    __shared__ float reps[256];
    int tid = threadIdx.x;
    ql[tid] = q[((size_t)bn * L_ + l) * HF_ + tid];
    __syncthreads();
    // scores (already scaled via q)
    for (int s = tid; s < S_; s += 256) {
        const float* krow = kv + (size_t)s * 512;
        #pragma unroll
        for (int h = 0; h < NH_; h++) {
            float acc = 0.f;
            const float* qh = &ql[h * 32];
            const float* kh = &krow[h * 32];
            #pragma unroll
            for (int e = 0; e < 32; e++) acc += qh[e] * kh[e];
            sc[h][s] = acc;
        }
    }
    __syncthreads();
    // softmax: wave w handles heads 2w, 2w+1
    int wid = tid >> 6, lane = tid & 63;
    for (int hh = 0; hh < 2; hh++) {
        int h = wid * 2 + hh;
        float mx = -1e30f;
        for (int s = lane; s < S_; s += 64) mx = fmaxf(mx, sc[h][s]);
        for (int o = 32; o > 0; o >>= 1) mx = fmaxf(mx, __shfl_xor(mx, o, 64));
        float sum = 0.f;
        for (int s = lane; s < S_; s += 64) {
            float e = expf(sc[h][s] - mx);
            sc[h][s] = e;
            sum += e;
        }
        for (int o = 32; o > 0; o >>= 1) sum += __shfl_xor(sum, o, 64);
        if (lane == 0) rden[h] = 1.0f / sum;
    }
    __syncthreads();
    // rep[h][e], tid = h*32+e
    {
        int h = tid >> 5;
        float acc = 0.f;
        const float* vcol = kv + 256 + tid;
        const float* sch = sc[h];
        #pragma unroll 4
        for (int s = 0; s < S_; s++) acc += sch[s] * vcol[(size_t)s * 512];
        reps[tid] = acc * rden[h];
    }
    __syncthreads();
    if (tid < DFF_) {
        float acc = bo[tid];
        const float* wrow = wo + (size_t)tid * HF_;
        #pragma unroll 8
        for (int c = 0; c < HF_; c++) acc += reps[c] * wrow[c];
        out32[((size_t)bn * L_ + l) * DFF_ + tid] = acc;
    }
}

// ---------------- head GEMM + de-normalize ----------------
__global__ __launch_bounds__(256) void k_head(const float* __restrict__ out32,
                                              const float* __restrict__ hw,
                                              const float* __restrict__ hb,
                                              const float* __restrict__ mean_i,
                                              const float* __restrict__ std_i,
                                              float* __restrict__ out) {
    int bn = blockIdx.x, b = bn / N_, n = bn % N_;
    __shared__ float dt[2048];
    for (int i = threadIdx.x; i < 2048; i += 256) dt[i] = out32[(size_t)bn * 2048 + i];
    __syncthreads();
    float m = mean_i[bn], sd = std_i[bn];
    for (int p = threadIdx.x; p < PRED_; p += 256) {
        float acc = hb[p];
        const float* w = hw + (size_t)p * HNF_;
        for (int f = 0; f < DFF_; f++) {
            const float* wf = w + f * 64;
            #pragma unroll
            for (int ll = 0; ll < 64; ll++) acc += dt[ll * 32 + f] * wf[ll];
        }
        out[(size_t)b * PRED_ * N_ + (size_t)p * N_ + n] = acc * sd + m;
    }
}

extern "C" void kernel_launch(void* const* d_in, const int* in_sizes, int n_in,
                              void* d_out, int out_size, void* d_ws, size_t ws_size,
                              hipStream_t stream) {
    const float* x_enc   = (const float*)d_in[0];
    const float* conv_w  = (const float*)d_in[1];
    const float* word_emb= (const float*)d_in[2];
    const float* map_w   = (const float*)d_in[3];
    const float* map_b   = (const float*)d_in[4];
    const float* wq      = (const float*)d_in[5];
    const float* bq      = (const float*)d_in[6];
    const float* wk      = (const float*)d_in[7];
    const float* bk      = (const float*)d_in[8];
    const float* wv      = (const float*)d_in[9];
    const float* bv      = (const float*)d_in[10];
    const float* wo      = (const float*)d_in[11];
    const float* bo      = (const float*)d_in[12];
    const float* head_w  = (const float*)d_in[13];
    const float* head_b  = (const float*)d_in[14];

    float* ws = (float*)d_ws;
    float* mean_w = ws + 0;
    float* std_w  = ws + 256;
    float* wsum_w = ws + 512;
    float* enc_w  = ws + 1024;
    float* q_w    = enc_w + (size_t)BN_ * 2048;          // 224*2048
    float* E_w    = q_w + (size_t)BN_ * L_ * HF_;        // 224*16384
    float* kv_w   = E_w + (size_t)V_ * 512;              // 32000*512
    float* o32_w  = kv_w + (size_t)S_ * 512;             // 1000*512
    float* cp_w   = o32_w + (size_t)BN_ * 2048;          // KSPLIT*1000*512

    k_stats<<<BN_, 256, 0, stream>>>(x_enc, mean_w, std_w);
    k_wsum<<<512, 256, 0, stream>>>(wk, wv, wsum_w);
    k_enc<<<BN_, 256, 0, stream>>>(x_enc, conv_w, mean_w, std_w, enc_w);
    k_q<<<BN_, 256, 0, stream>>>(enc_w, wq, bq, q_w);
    k_gemm1<<<dim3(V_ / 128, 4), 256, 0, stream>>>(word_emb, wk, wv, E_w);
    k_gemm2<<<dim3(8, 4, KSPLIT), 256, 0, stream>>>(map_w, E_w, cp_w);
    k_red<<<(S_ * 512 + 255) / 256, 256, 0, stream>>>(cp_w, map_b, wsum_w, bk, bv, kv_w);
    k_attn<<<dim3(L_, BN_), 256, 0, stream>>>(q_w, kv_w, wo, bo, o32_w);
    k_head<<<BN_, 256, 0, stream>>>(o32_w, head_w, head_b, mean_w, std_w, (float*)d_out);
}

// Round 2
// 2844.449 us; speedup vs baseline: 2.7271x; 2.7271x over previous
//
#include <hip/hip_runtime.h>
#include <math.h>

constexpr int B_ = 32, T_ = 512, N_ = 7, BN_ = 224;
constexpr int L_ = 64, DM_ = 32, PLEN_ = 16;
constexpr int HF_ = 256, NH_ = 8, DFF_ = 32;
constexpr int S_ = 1000, DLLM_ = 4096, V_ = 32000;
constexpr int PRED_ = 96, HNF_ = 2048;
constexpr int KSPLIT = 16, KCH = 2000;   // GEMM2 split-K: 16 chunks * 2000 = 32000

// ---------------- stats: mean/stdev per (b,n) ----------------
__global__ __launch_bounds__(256) void k_stats(const float* __restrict__ x,
                                               float* __restrict__ mean_o,
                                               float* __restrict__ std_o) {
    int bn = blockIdx.x, b = bn / N_, n = bn % N_;
    const float* xp = x + (size_t)b * T_ * N_ + n;
    float s = 0.f, sq = 0.f;
    for (int t = threadIdx.x; t < T_; t += 256) { float v = xp[(size_t)t * N_]; s += v; sq += v * v; }
    for (int o = 32; o > 0; o >>= 1) { s += __shfl_down(s, o, 64); sq += __shfl_down(sq, o, 64); }
    __shared__ float rs[4], rq[4];
    int wid = threadIdx.x >> 6, lane = threadIdx.x & 63;
    if (lane == 0) { rs[wid] = s; rq[wid] = sq; }
    __syncthreads();
    if (threadIdx.x == 0) {
        float S = rs[0] + rs[1] + rs[2] + rs[3];
        float Q = rq[0] + rq[1] + rq[2] + rq[3];
        float m = S / T_;
        float var = Q / T_ - m * m;
        mean_o[bn] = m;
        std_o[bn] = sqrtf(var + 1e-5f);
    }
}

// ---------------- wsum[c] = sum_d wkv[c][d] (for map_b folding) ----------------
__global__ __launch_bounds__(256) void k_wsum(const float* __restrict__ wk,
                                              const float* __restrict__ wv,
                                              float* __restrict__ wsum) {
    int c = blockIdx.x;
    const float* row = (c < HF_) ? wk + (size_t)c * DLLM_ : wv + (size_t)(c - HF_) * DLLM_;
    float s = 0.f;
    for (int d = threadIdx.x; d < DLLM_; d += 256) s += row[d];
    for (int o = 32; o > 0; o >>= 1) s += __shfl_down(s, o, 64);
    __shared__ float rs[4];
    int wid = threadIdx.x >> 6, lane = threadIdx.x & 63;
    if (lane == 0) rs[wid] = s;
    __syncthreads();
    if (threadIdx.x == 0) wsum[c] = rs[0] + rs[1] + rs[2] + rs[3];
}

// ---------------- normalize + patch + conv embed: enc[bn][l][o] ----------------
__global__ __launch_bounds__(256) void k_enc(const float* __restrict__ x,
                                             const float* __restrict__ conv_w,
                                             const float* __restrict__ mean_i,
                                             const float* __restrict__ std_i,
                                             float* __restrict__ enc) {
    int bn = blockIdx.x, b = bn / N_, n = bn % N_;
    __shared__ float xn[520];
    __shared__ float cw[DM_ * PLEN_ * 3];  // [o][i][t] = o*48+i*3+t
    float m = mean_i[bn], rstd = 1.0f / std_i[bn];
    for (int i = threadIdx.x; i < DM_ * PLEN_ * 3; i += 256) cw[i] = conv_w[i];
    const float* xp = x + (size_t)b * T_ * N_ + n;
    for (int t = threadIdx.x; t < T_; t += 256) xn[t] = (xp[(size_t)t * N_] - m) * rstd;
    __syncthreads();
    if (threadIdx.x < 8) xn[T_ + threadIdx.x] = xn[T_ - 1];
    __syncthreads();
    for (int idx = threadIdx.x; idx < L_ * DM_; idx += 256) {
        int l = idx >> 5, o = idx & 31;
        float acc = 0.f;
        #pragma unroll
        for (int t = 0; t < 3; t++) {
            int col = l + t;  // padded col 0..65
            int pcol = (col == 0) ? 63 : ((col == 65) ? 0 : col - 1);
            const float* xb = &xn[pcol * 8];
            const float* cwb = &cw[o * 48 + t];
            #pragma unroll
            for (int i = 0; i < 16; i++) acc += xb[i] * cwb[i * 3];
        }
        enc[(size_t)bn * 2048 + idx] = acc;
    }
}

// ---------------- q = (enc @ wq^T + bq) * scale ----------------
__global__ __launch_bounds__(256) void k_q(const float* __restrict__ enc,
                                           const float* __restrict__ wq,
                                           const float* __restrict__ bq,
                                           float* __restrict__ qo) {
    int bn = blockIdx.x;
    __shared__ float et[2048];
    __shared__ float wqs[HF_ * DM_];
    for (int i = threadIdx.x; i < 2048; i += 256) et[i] = enc[(size_t)bn * 2048 + i];
    for (int i = threadIdx.x; i < HF_ * DM_; i += 256) wqs[i] = wq[i];
    __syncthreads();
    const float scale = 0.17677669529663687f;  // 1/sqrt(32)
    for (int idx = threadIdx.x; idx < L_ * HF_; idx += 256) {
        int l = idx >> 8, c = idx & 255;
        float acc = bq[c];
        const float* e = &et[l * 32];
        const float* w = &wqs[c * 32];
        #pragma unroll
        for (int k = 0; k < 32; k++) acc += e[k] * w[k];
        qo[(size_t)bn * L_ * HF_ + idx] = acc * scale;
    }
}

// ---------------- GEMM1: E[32000][512] = word_emb @ [wk;wv]^T ----------------
__global__ __launch_bounds__(256) void k_gemm1(const float* __restrict__ A,
                                               const float* __restrict__ Wk,
                                               const float* __restrict__ Wv,
                                               float* __restrict__ C) {
    __shared__ float As[16][136];
    __shared__ float Bs[16][136];
    const int m0 = blockIdx.x * 128, n0 = blockIdx.y * 128;
    const float* Brow = (n0 < HF_) ? Wk + (size_t)n0 * DLLM_ : Wv + (size_t)(n0 - HF_) * DLLM_;
    const int tid = threadIdx.x, tx = tid & 15, ty = tid >> 4;
    float acc[8][8] = {};
    for (int k0 = 0; k0 < DLLM_; k0 += 16) {
        #pragma unroll
        for (int i = 0; i < 2; i++) {
            int f = i * 256 + tid;
            int r = f >> 2, c = (f & 3) * 4;
            float4 av = *(const float4*)(A + (size_t)(m0 + r) * DLLM_ + k0 + c);
            float4 bv = *(const float4*)(Brow + (size_t)r * DLLM_ + k0 + c);
            As[c + 0][r] = av.x; As[c + 1][r] = av.y; As[c + 2][r] = av.z; As[c + 3][r] = av.w;
            Bs[c + 0][r] = bv.x; Bs[c + 1][r] = bv.y; Bs[c + 2][r] = bv.z; Bs[c + 3][r] = bv.w;
        }
        __syncthreads();
        #pragma unroll
        for (int kk = 0; kk < 16; kk++) {
            float4 a0 = *(const float4*)&As[kk][ty * 8];
            float4 a1 = *(const float4*)&As[kk][ty * 8 + 4];
            float4 b0 = *(const float4*)&Bs[kk][tx * 8];
            float4 b1 = *(const float4*)&Bs[kk][tx * 8 + 4];
            float a[8] = {a0.x, a0.y, a0.z, a0.w, a1.x, a1.y, a1.z, a1.w};
            float b[8] = {b0.x, b0.y, b0.z, b0.w, b1.x, b1.y, b1.z, b1.w};
            #pragma unroll
            for (int i2 = 0; i2 < 8; i2++)
                #pragma unroll
                for (int j = 0; j < 8; j++) acc[i2][j] += a[i2] * b[j];
        }
        __syncthreads();
    }
    for (int i2 = 0; i2 < 8; i2++) {
        size_t m = m0 + ty * 8 + i2;
        float* crow = C + m * 512 + n0 + tx * 8;
        #pragma unroll
        for (int j = 0; j < 8; j++) crow[j] = acc[i2][j];
    }
}

// ---------------- GEMM2 (split-K partials) ----------------
__global__ __launch_bounds__(256) void k_gemm2(const float* __restrict__ A,
                                               const float* __restrict__ B,
                                               float* __restrict__ Cp) {
    __shared__ float As[16][136];
    __shared__ float Bs[16][136];
    const int m0 = blockIdx.x * 128, n0 = blockIdx.y * 128;
    const int kz = blockIdx.z;
    const int kbeg = kz * KCH, kend = kbeg + KCH;
    const int tid = threadIdx.x, tx = tid & 15, ty = tid >> 4;
    float acc[8][8] = {};
    for (int k0 = kbeg; k0 < kend; k0 += 16) {
        #pragma unroll
        for (int i = 0; i < 2; i++) {
            int f = i * 256 + tid;
            int r = f >> 2, c = (f & 3) * 4;
            int m = m0 + r;
            float4 av = (m < S_) ? *(const float4*)(A + (size_t)m * V_ + k0 + c)
                                 : make_float4(0.f, 0.f, 0.f, 0.f);
            As[c + 0][r] = av.x; As[c + 1][r] = av.y; As[c + 2][r] = av.z; As[c + 3][r] = av.w;
            int rk = f >> 5, cn = (f & 31) * 4;
            float4 bv = *(const float4*)(B + (size_t)(k0 + rk) * 512 + n0 + cn);
            *(float4*)&Bs[rk][cn] = bv;
        }
        __syncthreads();
        #pragma unroll
        for (int kk = 0; kk < 16; kk++) {
            float4 a0 = *(const float4*)&As[kk][ty * 8];
            float4 a1 = *(const float4*)&As[kk][ty * 8 + 4];
            float4 b0 = *(const float4*)&Bs[kk][tx * 8];
            float4 b1 = *(const float4*)&Bs[kk][tx * 8 + 4];
            float a[8] = {a0.x, a0.y, a0.z, a0.w, a1.x, a1.y, a1.z, a1.w};
            float b[8] = {b0.x, b0.y, b0.z, b0.w, b1.x, b1.y, b1.z, b1.w};
            #pragma unroll
            for (int i2 = 0; i2 < 8; i2++)
                #pragma unroll
                for (int j = 0; j < 8; j++) acc[i2][j] += a[i2] * b[j];
        }
        __syncthreads();
    }
    for (int i2 = 0; i2 < 8; i2++) {
        int m = m0 + ty * 8 + i2;
        if (m < S_) {
            float* crow = Cp + ((size_t)kz * S_ + m) * 512 + n0 + tx * 8;
            #pragma unroll
            for (int j = 0; j < 8; j++) crow[j] = acc[i2][j];
        }
    }
}

// ---------------- reduce split-K + bias: KV[t][c] ----------------
__global__ __launch_bounds__(256) void k_red(const float* __restrict__ Cp,
                                             const float* __restrict__ mb,
                                             const float* __restrict__ wsum,
                                             const float* __restrict__ bk,
                                             const float* __restrict__ bv,
                                             float* __restrict__ KV) {
    int idx = blockIdx.x * 256 + threadIdx.x;
    if (idx >= S_ * 512) return;
    int m = idx >> 9, n = idx & 511;
    float s = 0.f;
    #pragma unroll
    for (int z = 0; z < KSPLIT; z++) s += Cp[(size_t)z * S_ * 512 + idx];
    float bias = (n < HF_) ? bk[n] : bv[n - HF_];
    KV[idx] = s + mb[m] * wsum[n] + bias;
}

// ---------------- flash attention per (h, bn): rep[bn][c][l] (transposed) ----------------
constexpr int TS = 128;  // s-tile
__global__ __launch_bounds__(256) void k_attn(const float* __restrict__ q,
                                              const float* __restrict__ kv,
                                              float* __restrict__ rep) {
    const int h = blockIdx.x, bn = blockIdx.y;
    __shared__ float Ks[TS][36];
    __shared__ float Vs[TS][36];
    __shared__ float sm[4][64][2];
    __shared__ float buf[64][33];
    const int tid = threadIdx.x;
    const int l = tid & 63, wid = tid >> 6;

    // q fragment for this thread's row (scale already folded in)
    float qreg[32];
    const float* qp = q + ((size_t)bn * L_ + l) * HF_ + h * 32;
    #pragma unroll
    for (int e = 0; e < 32; e += 4) {
        float4 v = *(const float4*)(qp + e);
        qreg[e] = v.x; qreg[e + 1] = v.y; qreg[e + 2] = v.z; qreg[e + 3] = v.w;
    }

    float m = -1e30f, sum = 0.f;
    float acc[32] = {};

    for (int s0 = 0; s0 < S_; s0 += TS) {
        // stage K,V tile [TS][32] (padded to 36 for write bank-spread)
        for (int idx = tid; idx < TS * 8; idx += 256) {
            int r = idx >> 3, c4 = (idx & 7) * 4;
            int s = s0 + r;
            float4 kx = make_float4(0.f, 0.f, 0.f, 0.f);
            float4 vx = kx;
            if (s < S_) {
                kx = *(const float4*)(kv + (size_t)s * 512 + h * 32 + c4);
                vx = *(const float4*)(kv + (size_t)s * 512 + 256 + h * 32 + c4);
            }
            *(float4*)&Ks[r][c4] = kx;
            *(float4*)&Vs[r][c4] = vx;
        }
        __syncthreads();

        const int sbase = wid * 32;
        float sc[32];
        #pragma unroll 4
        for (int j = 0; j < 32; j++) {
            int sg = s0 + sbase + j;
            float d = 0.f;
            const float* kr = &Ks[sbase + j][0];
            #pragma unroll
            for (int e = 0; e < 32; e++) d += qreg[e] * kr[e];
            sc[j] = (sg < S_) ? d : -1e30f;
        }
        float tmax = -1e30f;
        #pragma unroll
        for (int j = 0; j < 32; j++) tmax = fmaxf(tmax, sc[j]);
        float mnew = fmaxf(m, tmax);
        float rescale = __expf(m - mnew);
        sum *= rescale;
        #pragma unroll
        for (int e = 0; e < 32; e++) acc[e] *= rescale;
        #pragma unroll 2
        for (int j = 0; j < 32; j++) {
            float p = __expf(sc[j] - mnew);
            sum += p;
            const float* vr = &Vs[sbase + j][0];
            #pragma unroll
            for (int e = 0; e < 32; e++) acc[e] += p * vr[e];
        }
        m = mnew;
        __syncthreads();
    }

    // cross-wave softmax combine (deterministic)
    sm[wid][l][0] = m;
    sm[wid][l][1] = sum;
    __syncthreads();
    float gm = fmaxf(fmaxf(sm[0][l][0], sm[1][l][0]), fmaxf(sm[2][l][0], sm[3][l][0]));
    float gden = 0.f;
    #pragma unroll
    for (int w = 0; w < 4; w++) gden += sm[w][l][1] * __expf(sm[w][l][0] - gm);
    float f = __expf(m - gm) / gden;
    for (int i = tid; i < 64 * 33; i += 256) ((float*)buf)[i] = 0.f;
    __syncthreads();
    for (int w = 0; w < 4; w++) {
        if (wid == w) {
            #pragma unroll
            for (int e = 0; e < 32; e++) buf[l][e] += acc[e] * f;
        }
        __syncthreads();
    }
    // write rep transposed: rep[bn][h*32+e][l] for coalesced k_out reads
    for (int idx = tid; idx < 2048; idx += 256) {
        int ll = idx & 63, e = idx >> 6;
        rep[((size_t)bn * HF_ + h * 32 + e) * 64 + ll] = buf[ll][e];
    }
}

// ---------------- out32[bn][l][e] = bo[e] + sum_c rep[bn][c][l] * wo[e][c] ----------------
__global__ __launch_bounds__(256) void k_out(const float* __restrict__ rep,
                                             const float* __restrict__ wo,
                                             const float* __restrict__ bo,
                                             float* __restrict__ out32) {
    const int bn = blockIdx.x;
    __shared__ float woT[HF_][32];  // woT[c][e] = wo[e][c]
    const int tid = threadIdx.x;
    for (int idx = tid; idx < HF_ * 32; idx += 256) {
        int e = idx & 31, c = idx >> 5;
        woT[c][e] = wo[(size_t)e * HF_ + c];
    }
    __syncthreads();
    const int l = tid & 63, e0 = (tid >> 6) * 8;
    float acc[8];
    #pragma unroll
    for (int i = 0; i < 8; i++) acc[i] = bo[e0 + i];
    const float* rp = rep + (size_t)bn * HF_ * 64 + l;
    for (int c = 0; c < HF_; c++) {
        float rv = rp[(size_t)c * 64];
        #pragma unroll
        for (int i = 0; i < 8; i++) acc[i] += rv * woT[c][e0 + i];
    }
    float* op = out32 + ((size_t)bn * L_ + l) * 32 + e0;
    #pragma unroll
    for (int i = 0; i < 8; i++) op[i] = acc[i];
}

// ---------------- head GEMM + de-normalize ----------------
__global__ __launch_bounds__(256) void k_head(const float* __restrict__ out32,
                                              const float* __restrict__ hw,
                                              const float* __restrict__ hb,
                                              const float* __restrict__ mean_i,
                                              const float* __restrict__ std_i,
                                              float* __restrict__ out) {
    int bn = blockIdx.x, b = bn / N_, n = bn % N_;
    __shared__ float dt[2048];
    for (int i = threadIdx.x; i < 2048; i += 256) dt[i] = out32[(size_t)bn * 2048 + i];
    __syncthreads();
    float m = mean_i[bn], sd = std_i[bn];
    for (int p = threadIdx.x; p < PRED_; p += 256) {
        float acc = hb[p];
        const float* w = hw + (size_t)p * HNF_;
        for (int f = 0; f < DFF_; f++) {
            const float* wf = w + f * 64;
            #pragma unroll
            for (int ll = 0; ll < 64; ll++) acc += dt[ll * 32 + f] * wf[ll];
        }
        out[(size_t)b * PRED_ * N_ + (size_t)p * N_ + n] = acc * sd + m;
    }
}

extern "C" void kernel_launch(void* const* d_in, const int* in_sizes, int n_in,
                              void* d_out, int out_size, void* d_ws, size_t ws_size,
                              hipStream_t stream) {
    const float* x_enc   = (const float*)d_in[0];
    const float* conv_w  = (const float*)d_in[1];
    const float* word_emb= (const float*)d_in[2];
    const float* map_w   = (const float*)d_in[3];
    const float* map_b   = (const float*)d_in[4];
    const float* wq      = (const float*)d_in[5];
    const float* bq      = (const float*)d_in[6];
    const float* wk      = (const float*)d_in[7];
    const float* bk      = (const float*)d_in[8];
    const float* wv      = (const float*)d_in[9];
    const float* bv      = (const float*)d_in[10];
    const float* wo      = (const float*)d_in[11];
    const float* bo      = (const float*)d_in[12];
    const float* head_w  = (const float*)d_in[13];
    const float* head_b  = (const float*)d_in[14];

    float* ws = (float*)d_ws;
    float* mean_w = ws + 0;
    float* std_w  = ws + 256;
    float* wsum_w = ws + 512;
    float* enc_w  = ws + 1024;
    float* q_w    = enc_w + (size_t)BN_ * 2048;          // 224*2048
    float* E_w    = q_w + (size_t)BN_ * L_ * HF_;        // 224*16384
    float* kv_w   = E_w + (size_t)V_ * 512;              // 32000*512
    float* o32_w  = kv_w + (size_t)S_ * 512;             // 1000*512
    float* cp_w   = o32_w + (size_t)BN_ * 2048;          // KSPLIT*1000*512
    float* rep_w  = cp_w;  // alias: cp dead after k_red; rep = 224*256*64 fits

    k_stats<<<BN_, 256, 0, stream>>>(x_enc, mean_w, std_w);
    k_wsum<<<512, 256, 0, stream>>>(wk, wv, wsum_w);
    k_enc<<<BN_, 256, 0, stream>>>(x_enc, conv_w, mean_w, std_w, enc_w);
    k_q<<<BN_, 256, 0, stream>>>(enc_w, wq, bq, q_w);
    k_gemm1<<<dim3(V_ / 128, 4), 256, 0, stream>>>(word_emb, wk, wv, E_w);
    k_gemm2<<<dim3(8, 4, KSPLIT), 256, 0, stream>>>(map_w, E_w, cp_w);
    k_red<<<(S_ * 512 + 255) / 256, 256, 0, stream>>>(cp_w, map_b, wsum_w, bk, bv, kv_w);
    k_attn<<<dim3(NH_, BN_), 256, 0, stream>>>(q_w, kv_w, rep_w);
    k_out<<<BN_, 256, 0, stream>>>(rep_w, wo, bo, o32_w);
    k_head<<<BN_, 256, 0, stream>>>(o32_w, head_w, head_b, mean_w, std_w, (float*)d_out);
}

// Round 3
// 797.405 us; speedup vs baseline: 9.7279x; 3.5671x over previous
//
#include <hip/hip_runtime.h>
#include <math.h>

constexpr int B_ = 32, T_ = 512, N_ = 7, BN_ = 224;
constexpr int L_ = 64, DM_ = 32, PLEN_ = 16;
constexpr int HF_ = 256, NH_ = 8, DFF_ = 32;
constexpr int S_ = 1000, DLLM_ = 4096, V_ = 32000;
constexpr int PRED_ = 96, HNF_ = 2048;
constexpr int KSPLIT2 = 8, KCH2 = 4000;  // GEMM2 split-K

typedef short bf16x8 __attribute__((ext_vector_type(8)));
typedef float f32x4 __attribute__((ext_vector_type(4)));

__device__ inline ushort f2bf(float x) {
    union { float f; uint u; } v; v.f = x;
    uint r = v.u + 0x7fffu + ((v.u >> 16) & 1u);  // RNE
    return (ushort)(r >> 16);
}
__device__ inline uint pk(float a, float b) {
    return (uint)f2bf(a) | ((uint)f2bf(b) << 16);
}

// ---------------- stats: mean/stdev per (b,n) ----------------
__global__ __launch_bounds__(256) void k_stats(const float* __restrict__ x,
                                               float* __restrict__ mean_o,
                                               float* __restrict__ std_o) {
    int bn = blockIdx.x, b = bn / N_, n = bn % N_;
    const float* xp = x + (size_t)b * T_ * N_ + n;
    float s = 0.f, sq = 0.f;
    for (int t = threadIdx.x; t < T_; t += 256) { float v = xp[(size_t)t * N_]; s += v; sq += v * v; }
    for (int o = 32; o > 0; o >>= 1) { s += __shfl_down(s, o, 64); sq += __shfl_down(sq, o, 64); }
    __shared__ float rs[4], rq[4];
    int wid = threadIdx.x >> 6, lane = threadIdx.x & 63;
    if (lane == 0) { rs[wid] = s; rq[wid] = sq; }
    __syncthreads();
    if (threadIdx.x == 0) {
        float S = rs[0] + rs[1] + rs[2] + rs[3];
        float Q = rq[0] + rq[1] + rq[2] + rq[3];
        float m = S / T_;
        float var = Q / T_ - m * m;
        mean_o[bn] = m;
        std_o[bn] = sqrtf(var + 1e-5f);
    }
}

// ---------------- wsum[c] = sum_d wkv[c][d] (exact f32, for map_b folding) ----------------
__global__ __launch_bounds__(256) void k_wsum(const float* __restrict__ wk,
                                              const float* __restrict__ wv,
                                              float* __restrict__ wsum) {
    int c = blockIdx.x;
    const float* row = (c < HF_) ? wk + (size_t)c * DLLM_ : wv + (size_t)(c - HF_) * DLLM_;
    float s = 0.f;
    for (int d = threadIdx.x; d < DLLM_; d += 256) s += row[d];
    for (int o = 32; o > 0; o >>= 1) s += __shfl_down(s, o, 64);
    __shared__ float rs[4];
    int wid = threadIdx.x >> 6, lane = threadIdx.x & 63;
    if (lane == 0) rs[wid] = s;
    __syncthreads();
    if (threadIdx.x == 0) wsum[c] = rs[0] + rs[1] + rs[2] + rs[3];
}

// ---------------- normalize + patch + conv embed ----------------
__global__ __launch_bounds__(256) void k_enc(const float* __restrict__ x,
                                             const float* __restrict__ conv_w,
                                             const float* __restrict__ mean_i,
                                             const float* __restrict__ std_i,
                                             float* __restrict__ enc) {
    int bn = blockIdx.x, b = bn / N_, n = bn % N_;
    __shared__ float xn[520];
    __shared__ float cw[DM_ * PLEN_ * 3];
    float m = mean_i[bn], rstd = 1.0f / std_i[bn];
    for (int i = threadIdx.x; i < DM_ * PLEN_ * 3; i += 256) cw[i] = conv_w[i];
    const float* xp = x + (size_t)b * T_ * N_ + n;
    for (int t = threadIdx.x; t < T_; t += 256) xn[t] = (xp[(size_t)t * N_] - m) * rstd;
    __syncthreads();
    if (threadIdx.x < 8) xn[T_ + threadIdx.x] = xn[T_ - 1];
    __syncthreads();
    for (int idx = threadIdx.x; idx < L_ * DM_; idx += 256) {
        int l = idx >> 5, o = idx & 31;
        float acc = 0.f;
        #pragma unroll
        for (int t = 0; t < 3; t++) {
            int col = l + t;
            int pcol = (col == 0) ? 63 : ((col == 65) ? 0 : col - 1);
            const float* xb = &xn[pcol * 8];
            const float* cwb = &cw[o * 48 + t];
            #pragma unroll
            for (int i = 0; i < 16; i++) acc += xb[i] * cwb[i * 3];
        }
        enc[(size_t)bn * 2048 + idx] = acc;
    }
}

// ---------------- q = (enc @ wq^T + bq) * scale ----------------
__global__ __launch_bounds__(256) void k_q(const float* __restrict__ enc,
                                           const float* __restrict__ wq,
                                           const float* __restrict__ bq,
                                           float* __restrict__ qo) {
    int bn = blockIdx.x;
    __shared__ float et[2048];
    __shared__ float wqs[HF_ * DM_];
    for (int i = threadIdx.x; i < 2048; i += 256) et[i] = enc[(size_t)bn * 2048 + i];
    for (int i = threadIdx.x; i < HF_ * DM_; i += 256) wqs[i] = wq[i];
    __syncthreads();
    const float scale = 0.17677669529663687f;
    for (int idx = threadIdx.x; idx < L_ * HF_; idx += 256) {
        int l = idx >> 8, c = idx & 255;
        float acc = bq[c];
        const float* e = &et[l * 32];
        const float* w = &wqs[c * 32];
        #pragma unroll
        for (int k = 0; k < 32; k++) acc += e[k] * w[k];
        qo[(size_t)bn * L_ * HF_ + idx] = acc * scale;
    }
}

// ---------------- cvt wk,wv -> wkv_bf [512][4096] bf16 ----------------
__global__ __launch_bounds__(256) void k_cvt_wkv(const float* __restrict__ wk,
                                                 const float* __restrict__ wv,
                                                 ushort* __restrict__ out) {
    int g = blockIdx.x * 256 + threadIdx.x;
    int e = g * 8;  // total 512*4096 = 2097152
    const float* src = (e < HF_ * DLLM_) ? wk + e : wv + (e - HF_ * DLLM_);
    float4 x = *(const float4*)src, y = *(const float4*)(src + 4);
    uint4 w; w.x = pk(x.x, x.y); w.y = pk(x.z, x.w); w.z = pk(y.x, y.y); w.w = pk(y.z, y.w);
    *(uint4*)(out + e) = w;
}

// ---------------- GEMM1 (bf16 MFMA): E_T[512][32000] = (word_emb @ wkv^T)^T ----------------
// BM=128, BN=256, BK=32, 512 threads (8 waves, 2x4 of 64x64). A f32->bf16 in staging.
__global__ __launch_bounds__(512) void k_gemm1(const float* __restrict__ A,
                                               const ushort* __restrict__ Bw,
                                               ushort* __restrict__ ET) {
    __shared__ union {
        struct { ushort A[2][128 * 32]; ushort B[2][256 * 32]; } st;
        ushort C[256 * 72];
    } lds;
    const int tid = threadIdx.x;
    const int lane = tid & 63, wid = tid >> 6;
    const int wr = wid >> 2, wc = wid & 3;
    const int m0 = blockIdx.x * 128, n0 = blockIdx.y * 256;

    const int ar = tid >> 2, ak = (tid & 3) * 8;    // A: 8 f32/thread
    const int bn = tid >> 1, bk = (tid & 1) * 16;   // B: 16 bf16/thread
    const float* aptr = A + (size_t)(m0 + ar) * DLLM_ + ak;
    const ushort* bptr = Bw + (size_t)(n0 + bn) * DLLM_ + bk;

    f32x4 acc[4][4];
    #pragma unroll
    for (int i = 0; i < 4; i++)
        #pragma unroll
        for (int j = 0; j < 4; j++) acc[i][j] = (f32x4){0.f, 0.f, 0.f, 0.f};

    {   // prologue: stage tile 0 into buf 0
        float4 a0 = *(const float4*)aptr;
        float4 a1 = *(const float4*)(aptr + 4);
        uint4 b0 = *(const uint4*)bptr;
        uint4 b1 = *(const uint4*)(bptr + 8);
        uint4 wa; wa.x = pk(a0.x, a0.y); wa.y = pk(a0.z, a0.w); wa.z = pk(a1.x, a1.y); wa.w = pk(a1.z, a1.w);
        *(uint4*)&lds.st.A[0][tid * 8] = wa;
        *(uint4*)&lds.st.B[0][tid * 16] = b0;
        *(uint4*)&lds.st.B[0][tid * 16 + 8] = b1;
    }
    __syncthreads();

    int cur = 0;
    constexpr int NT = DLLM_ / 32;
    for (int t = 0; t < NT; ++t) {
        float4 a0, a1; uint4 b0, b1;
        const bool more = (t + 1 < NT);
        if (more) {
            const float* ap = aptr + (t + 1) * 32;
            a0 = *(const float4*)ap; a1 = *(const float4*)(ap + 4);
            const ushort* bp = bptr + (t + 1) * 32;
            b0 = *(const uint4*)bp; b1 = *(const uint4*)(bp + 8);
        }
        const ushort* Ab = lds.st.A[cur];
        const ushort* Bb = lds.st.B[cur];
        bf16x8 af[4], bfr[4];
        #pragma unroll
        for (int mi = 0; mi < 4; mi++)
            af[mi] = *(const bf16x8*)&Ab[(wr * 64 + mi * 16 + (lane & 15)) * 32 + (lane >> 4) * 8];
        #pragma unroll
        for (int ni = 0; ni < 4; ni++)
            bfr[ni] = *(const bf16x8*)&Bb[(wc * 64 + ni * 16 + (lane & 15)) * 32 + (lane >> 4) * 8];
        #pragma unroll
        for (int mi = 0; mi < 4; mi++)
            #pragma unroll
            for (int ni = 0; ni < 4; ni++)
                acc[mi][ni] = __builtin_amdgcn_mfma_f32_16x16x32_bf16(af[mi], bfr[ni], acc[mi][ni], 0, 0, 0);
        if (more) {
            int nb = cur ^ 1;
            uint4 wa; wa.x = pk(a0.x, a0.y); wa.y = pk(a0.z, a0.w); wa.z = pk(a1.x, a1.y); wa.w = pk(a1.z, a1.w);
            *(uint4*)&lds.st.A[nb][tid * 8] = wa;
            *(uint4*)&lds.st.B[nb][tid * 16] = b0;
            *(uint4*)&lds.st.B[nb][tid * 16 + 8] = b1;
        }
        __syncthreads();
        cur ^= 1;
    }

    // epilogue: transpose to E_T via LDS, two rounds over wr halves
    #pragma unroll
    for (int p = 0; p < 2; p++) {
        __syncthreads();
        if (wr == p) {
            #pragma unroll
            for (int mi = 0; mi < 4; mi++)
                #pragma unroll
                for (int ni = 0; ni < 4; ni++) {
                    int nl = wc * 64 + ni * 16 + (lane & 15);
                    int ml = mi * 16 + (lane >> 4) * 4;
                    uint2 w2;
                    w2.x = pk(acc[mi][ni][0], acc[mi][ni][1]);
                    w2.y = pk(acc[mi][ni][2], acc[mi][ni][3]);
                    *(uint2*)&lds.C[nl * 72 + ml] = w2;
                }
        }
        __syncthreads();
        {
            int r = tid >> 1, half = tid & 1;
            const uint4* src = (const uint4*)&lds.C[r * 72 + half * 32];
            ushort* dst = ET + (size_t)(n0 + r) * V_ + m0 + p * 64 + half * 32;
            uint4 v0 = src[0], v1 = src[1], v2 = src[2], v3 = src[3];
            *(uint4*)(dst + 0) = v0; *(uint4*)(dst + 8) = v1;
            *(uint4*)(dst + 16) = v2; *(uint4*)(dst + 24) = v3;
        }
    }
}

// ---------------- GEMM2 (bf16 MFMA, split-K): Cp[kz] = map_w[:,chunk] @ E_T[:,chunk]^T ----------------
// BM=128, BN=128, BK=32, 256 threads (4 waves, 2x2 of 64x64).
__global__ __launch_bounds__(256) void k_gemm2(const float* __restrict__ A,
                                               const ushort* __restrict__ ET,
                                               float* __restrict__ Cp) {
    __shared__ ushort As[2][128 * 32];
    __shared__ ushort Bs[2][128 * 32];
    const int tid = threadIdx.x, lane = tid & 63, wid = tid >> 6;
    const int wr = wid >> 1, wc = wid & 1;
    const int m0 = blockIdx.x * 128, n0 = blockIdx.y * 128, kz = blockIdx.z;
    const size_t kbase = (size_t)kz * KCH2;

    const int ar = tid >> 1, ak = (tid & 1) * 16;  // 16 elems/thread for both A and B
    const bool aval = (m0 + ar) < S_;
    const float* aptr = A + (size_t)(m0 + ar) * V_ + kbase + ak;
    const ushort* bptr = ET + (size_t)(n0 + ar) * V_ + kbase + ak;

    f32x4 acc[4][4];
    #pragma unroll
    for (int i = 0; i < 4; i++)
        #pragma unroll
        for (int j = 0; j < 4; j++) acc[i][j] = (f32x4){0.f, 0.f, 0.f, 0.f};

    {   // prologue
        float4 a0 = {0,0,0,0}, a1 = a0, a2 = a0, a3 = a0;
        if (aval) { a0 = *(const float4*)aptr; a1 = *(const float4*)(aptr + 4);
                    a2 = *(const float4*)(aptr + 8); a3 = *(const float4*)(aptr + 12); }
        uint4 b0 = *(const uint4*)bptr, b1 = *(const uint4*)(bptr + 8);
        uint4 w0, w1;
        w0.x = pk(a0.x, a0.y); w0.y = pk(a0.z, a0.w); w0.z = pk(a1.x, a1.y); w0.w = pk(a1.z, a1.w);
        w1.x = pk(a2.x, a2.y); w1.y = pk(a2.z, a2.w); w1.z = pk(a3.x, a3.y); w1.w = pk(a3.z, a3.w);
        *(uint4*)&As[0][tid * 16] = w0; *(uint4*)&As[0][tid * 16 + 8] = w1;
        *(uint4*)&Bs[0][tid * 16] = b0; *(uint4*)&Bs[0][tid * 16 + 8] = b1;
    }
    __syncthreads();

    int cur = 0;
    constexpr int NT = KCH2 / 32;  // 125
    for (int t = 0; t < NT; ++t) {
        float4 a0, a1, a2, a3; uint4 b0, b1;
        const bool more = (t + 1 < NT);
        if (more) {
            const float* ap = aptr + (t + 1) * 32;
            if (aval) { a0 = *(const float4*)ap; a1 = *(const float4*)(ap + 4);
                        a2 = *(const float4*)(ap + 8); a3 = *(const float4*)(ap + 12); }
            else { a0 = (float4){0,0,0,0}; a1 = a0; a2 = a0; a3 = a0; }
            const ushort* bp = bptr + (t + 1) * 32;
            b0 = *(const uint4*)bp; b1 = *(const uint4*)(bp + 8);
        }
        const ushort* Ab = As[cur];
        const ushort* Bb = Bs[cur];
        bf16x8 af[4], bfr[4];
        #pragma unroll
        for (int mi = 0; mi < 4; mi++)
            af[mi] = *(const bf16x8*)&Ab[(wr * 64 + mi * 16 + (lane & 15)) * 32 + (lane >> 4) * 8];
        #pragma unroll
        for (int ni = 0; ni < 4; ni++)
            bfr[ni] = *(const bf16x8*)&Bb[(wc * 64 + ni * 16 + (lane & 15)) * 32 + (lane >> 4) * 8];
        #pragma unroll
        for (int mi = 0; mi < 4; mi++)
            #pragma unroll
            for (int ni = 0; ni < 4; ni++)
                acc[mi][ni] = __builtin_amdgcn_mfma_f32_16x16x32_bf16(af[mi], bfr[ni], acc[mi][ni], 0, 0, 0);
        if (more) {
            int nb = cur ^ 1;
            uint4 w0, w1;
            w0.x = pk(a0.x, a0.y); w0.y = pk(a0.z, a0.w); w0.z = pk(a1.x, a1.y); w0.w = pk(a1.z, a1.w);
            w1.x = pk(a2.x, a2.y); w1.y = pk(a2.z, a2.w); w1.z = pk(a3.x, a3.y); w1.w = pk(a3.z, a3.w);
            *(uint4*)&As[nb][tid * 16] = w0; *(uint4*)&As[nb][tid * 16 + 8] = w1;
            *(uint4*)&Bs[nb][tid * 16] = b0; *(uint4*)&Bs[nb][tid * 16 + 8] = b1;
        }
        __syncthreads();
        cur ^= 1;
    }

    #pragma unroll
    for (int mi = 0; mi < 4; mi++)
        #pragma unroll
        for (int ni = 0; ni < 4; ni++)
            #pragma unroll
            for (int j = 0; j < 4; j++) {
                int m = m0 + wr * 64 + mi * 16 + (lane >> 4) * 4 + j;
                int n = n0 + wc * 64 + ni * 16 + (lane & 15);
                if (m < S_) Cp[((size_t)kz * S_ + m) * 512 + n] = acc[mi][ni][j];
            }
}

// ---------------- reduce split-K + exact bias ----------------
__global__ __launch_bounds__(256) void k_red(const float* __restrict__ Cp,
                                             const float* __restrict__ mb,
                                             const float* __restrict__ wsum,
                                             const float* __restrict__ bk,
                                             const float* __restrict__ bv,
                                             float* __restrict__ KV) {
    int idx = blockIdx.x * 256 + threadIdx.x;
    if (idx >= S_ * 512) return;
    int m = idx >> 9, n = idx & 511;
    float s = 0.f;
    #pragma unroll
    for (int z = 0; z < KSPLIT2; z++) s += Cp[(size_t)z * S_ * 512 + idx];
    float bias = (n < HF_) ? bk[n] : bv[n - HF_];
    KV[idx] = s + mb[m] * wsum[n] + bias;
}

// ---------------- flash attention per (h, bn) ----------------
constexpr int TS = 128;
__global__ __launch_bounds__(256) void k_attn(const float* __restrict__ q,
                                              const float* __restrict__ kv,
                                              float* __restrict__ rep) {
    const int h = blockIdx.x, bn = blockIdx.y;
    __shared__ float Ks[TS][36];
    __shared__ float Vs[TS][36];
    __shared__ float sm[4][64][2];
    __shared__ float buf[64][33];
    const int tid = threadIdx.x;
    const int l = tid & 63, wid = tid >> 6;

    float qreg[32];
    const float* qp = q + ((size_t)bn * L_ + l) * HF_ + h * 32;
    #pragma unroll
    for (int e = 0; e < 32; e += 4) {
        float4 v = *(const float4*)(qp + e);
        qreg[e] = v.x; qreg[e + 1] = v.y; qreg[e + 2] = v.z; qreg[e + 3] = v.w;
    }

    float m = -1e30f, sum = 0.f;
    float acc[32] = {};

    for (int s0 = 0; s0 < S_; s0 += TS) {
        for (int idx = tid; idx < TS * 8; idx += 256) {
            int r = idx >> 3, c4 = (idx & 7) * 4;
            int s = s0 + r;
            float4 kx = make_float4(0.f, 0.f, 0.f, 0.f);
            float4 vx = kx;
            if (s < S_) {
                kx = *(const float4*)(kv + (size_t)s * 512 + h * 32 + c4);
                vx = *(const float4*)(kv + (size_t)s * 512 + 256 + h * 32 + c4);
            }
            *(float4*)&Ks[r][c4] = kx;
            *(float4*)&Vs[r][c4] = vx;
        }
        __syncthreads();

        const int sbase = wid * 32;
        float sc[32];
        #pragma unroll 4
        for (int j = 0; j < 32; j++) {
            int sg = s0 + sbase + j;
            float d = 0.f;
            const float* kr = &Ks[sbase + j][0];
            #pragma unroll
            for (int e = 0; e < 32; e++) d += qreg[e] * kr[e];
            sc[j] = (sg < S_) ? d : -1e30f;
        }
        float tmax = -1e30f;
        #pragma unroll
        for (int j = 0; j < 32; j++) tmax = fmaxf(tmax, sc[j]);
        float mnew = fmaxf(m, tmax);
        float rescale = __expf(m - mnew);
        sum *= rescale;
        #pragma unroll
        for (int e = 0; e < 32; e++) acc[e] *= rescale;
        #pragma unroll 2
        for (int j = 0; j < 32; j++) {
            float p = __expf(sc[j] - mnew);
            sum += p;
            const float* vr = &Vs[sbase + j][0];
            #pragma unroll
            for (int e = 0; e < 32; e++) acc[e] += p * vr[e];
        }
        m = mnew;
        __syncthreads();
    }

    sm[wid][l][0] = m;
    sm[wid][l][1] = sum;
    __syncthreads();
    float gm = fmaxf(fmaxf(sm[0][l][0], sm[1][l][0]), fmaxf(sm[2][l][0], sm[3][l][0]));
    float gden = 0.f;
    #pragma unroll
    for (int w = 0; w < 4; w++) gden += sm[w][l][1] * __expf(sm[w][l][0] - gm);
    float f = __expf(m - gm) / gden;
    for (int i = tid; i < 64 * 33; i += 256) ((float*)buf)[i] = 0.f;
    __syncthreads();
    for (int w = 0; w < 4; w++) {
        if (wid == w) {
            #pragma unroll
            for (int e = 0; e < 32; e++) buf[l][e] += acc[e] * f;
        }
        __syncthreads();
    }
    for (int idx = tid; idx < 2048; idx += 256) {
        int ll = idx & 63, e = idx >> 6;
        rep[((size_t)bn * HF_ + h * 32 + e) * 64 + ll] = buf[ll][e];
    }
}

// ---------------- out32 = rep @ wo[0:32]^T + bo ----------------
__global__ __launch_bounds__(256) void k_out(const float* __restrict__ rep,
                                             const float* __restrict__ wo,
                                             const float* __restrict__ bo,
                                             float* __restrict__ out32) {
    const int bn = blockIdx.x;
    __shared__ float woT[HF_][32];
    const int tid = threadIdx.x;
    for (int idx = tid; idx < HF_ * 32; idx += 256) {
        int e = idx & 31, c = idx >> 5;
        woT[c][e] = wo[(size_t)e * HF_ + c];
    }
    __syncthreads();
    const int l = tid & 63, e0 = (tid >> 6) * 8;
    float acc[8];
    #pragma unroll
    for (int i = 0; i < 8; i++) acc[i] = bo[e0 + i];
    const float* rp = rep + (size_t)bn * HF_ * 64 + l;
    for (int c = 0; c < HF_; c++) {
        float rv = rp[(size_t)c * 64];
        #pragma unroll
        for (int i = 0; i < 8; i++) acc[i] += rv * woT[c][e0 + i];
    }
    float* op = out32 + ((size_t)bn * L_ + l) * 32 + e0;
    #pragma unroll
    for (int i = 0; i < 8; i++) op[i] = acc[i];
}

// ---------------- head GEMM + de-normalize ----------------
__global__ __launch_bounds__(256) void k_head(const float* __restrict__ out32,
                                              const float* __restrict__ hw,
                                              const float* __restrict__ hb,
                                              const float* __restrict__ mean_i,
                                              const float* __restrict__ std_i,
                                              float* __restrict__ out) {
    int bn = blockIdx.x, b = bn / N_, n = bn % N_;
    __shared__ float dt[2048];
    for (int i = threadIdx.x; i < 2048; i += 256) dt[i] = out32[(size_t)bn * 2048 + i];
    __syncthreads();
    float m = mean_i[bn], sd = std_i[bn];
    for (int p = threadIdx.x; p < PRED_; p += 256) {
        float acc = hb[p];
        const float* w = hw + (size_t)p * HNF_;
        for (int f = 0; f < DFF_; f++) {
            const float* wf = w + f * 64;
            #pragma unroll
            for (int ll = 0; ll < 64; ll++) acc += dt[ll * 32 + f] * wf[ll];
        }
        out[(size_t)b * PRED_ * N_ + (size_t)p * N_ + n] = acc * sd + m;
    }
}

extern "C" void kernel_launch(void* const* d_in, const int* in_sizes, int n_in,
                              void* d_out, int out_size, void* d_ws, size_t ws_size,
                              hipStream_t stream) {
    const float* x_enc   = (const float*)d_in[0];
    const float* conv_w  = (const float*)d_in[1];
    const float* word_emb= (const float*)d_in[2];
    const float* map_w   = (const float*)d_in[3];
    const float* map_b   = (const float*)d_in[4];
    const float* wq      = (const float*)d_in[5];
    const float* bq      = (const float*)d_in[6];
    const float* wk      = (const float*)d_in[7];
    const float* bk      = (const float*)d_in[8];
    const float* wv      = (const float*)d_in[9];
    const float* bv      = (const float*)d_in[10];
    const float* wo      = (const float*)d_in[11];
    const float* bo      = (const float*)d_in[12];
    const float* head_w  = (const float*)d_in[13];
    const float* head_b  = (const float*)d_in[14];

    float* ws = (float*)d_ws;
    float* mean_w = ws;                          // 256
    float* std_w  = ws + 256;                    // 256
    float* wsum_w = ws + 512;                    // 512
    float* enc_w  = ws + 1024;                   // 224*2048
    float* q_w    = enc_w + (size_t)BN_ * 2048;  // 224*16384
    float* kv_w   = q_w + (size_t)BN_ * L_ * HF_;// 1000*512
    float* o32_w  = kv_w + (size_t)S_ * 512;     // 224*2048
    float* cp_w   = o32_w + (size_t)BN_ * 2048;  // 8*1000*512
    float* rep_w  = cp_w;                        // alias: cp dead after k_red
    ushort* et_w  = (ushort*)(cp_w + (size_t)KSPLIT2 * S_ * 512);  // 512*32000 bf16
    ushort* wkv_w = et_w + (size_t)512 * V_;                       // 512*4096 bf16

    k_stats<<<BN_, 256, 0, stream>>>(x_enc, mean_w, std_w);
    k_wsum<<<512, 256, 0, stream>>>(wk, wv, wsum_w);
    k_enc<<<BN_, 256, 0, stream>>>(x_enc, conv_w, mean_w, std_w, enc_w);
    k_q<<<BN_, 256, 0, stream>>>(enc_w, wq, bq, q_w);
    k_cvt_wkv<<<(512 * DLLM_ / 8) / 256, 256, 0, stream>>>(wk, wv, wkv_w);
    k_gemm1<<<dim3(V_ / 128, 2), 512, 0, stream>>>(word_emb, wkv_w, et_w);
    k_gemm2<<<dim3(8, 4, KSPLIT2), 256, 0, stream>>>(map_w, et_w, cp_w);
    k_red<<<(S_ * 512 + 255) / 256, 256, 0, stream>>>(cp_w, map_b, wsum_w, bk, bv, kv_w);
    k_attn<<<dim3(NH_, BN_), 256, 0, stream>>>(q_w, kv_w, rep_w);
    k_out<<<BN_, 256, 0, stream>>>(rep_w, wo, bo, o32_w);
    k_head<<<BN_, 256, 0, stream>>>(o32_w, head_w, head_b, mean_w, std_w, (float*)d_out);
}